// Round 2
// baseline (1403.716 us; speedup 1.0000x reference)
//
#include <hip/hip_runtime.h>

#define B_ 16
#define NQ 2048
#define NK 2048
#define DH 128
#define NROWS (B_*NQ)
#define NEG (-1e10f)
#define INV 0.08838834764831843f   // 1/sqrt(128)

// ---------------- K1: S = mask ? -1e10 : (Q K^T) * inv  (raw scores) --------
// 128x128 tile per block, 8x8 micro-tile per thread, fp32.
// mask is int32 per harness contract (numpy bool -> int).
__global__ __launch_bounds__(256) void k_scores(
    const float* __restrict__ q, const float* __restrict__ k,
    const int* __restrict__ mask, float* __restrict__ S) {
  const int b  = blockIdx.z;
  const int qt = blockIdx.y << 7;
  const int kt = blockIdx.x << 7;
  __shared__ __align__(16) float Qs[32][132];  // [d][q], pad 132 (528B rows, 16B aligned)
  __shared__ __align__(16) float Ks[32][132];  // [d][k]
  const int t  = threadIdx.x;
  const int ty = t >> 4, tx = t & 15;
  float acc[8][8];
  #pragma unroll
  for (int i = 0; i < 8; i++)
    #pragma unroll
    for (int j = 0; j < 8; j++) acc[i][j] = 0.f;

  const float* qb = q + ((size_t)b*NQ + qt)*DH;
  const float* kb = k + ((size_t)b*NK + kt)*DH;

  for (int d0 = 0; d0 < DH; d0 += 32) {
    #pragma unroll
    for (int e = 0; e < 16; e++) {
      int f = (e<<8) + t;
      int row = f >> 5, col = f & 31;     // row: 0..127, col: 0..31
      Qs[col][row] = qb[(size_t)row*DH + d0 + col];
      Ks[col][row] = kb[(size_t)row*DH + d0 + col];
    }
    __syncthreads();
    #pragma unroll
    for (int dd = 0; dd < 32; dd++) {
      float av[8], bv[8];
      *(float4*)&av[0] = *(const float4*)&Qs[dd][ty*8];
      *(float4*)&av[4] = *(const float4*)&Qs[dd][ty*8+4];
      *(float4*)&bv[0] = *(const float4*)&Ks[dd][tx*8];
      *(float4*)&bv[4] = *(const float4*)&Ks[dd][tx*8+4];
      #pragma unroll
      for (int i = 0; i < 8; i++)
        #pragma unroll
        for (int j = 0; j < 8; j++)
          acc[i][j] = fmaf(av[i], bv[j], acc[i][j]);
    }
    __syncthreads();
  }

  #pragma unroll
  for (int i = 0; i < 8; i++) {
    size_t grow = (size_t)b*NQ + qt + ty*8 + i;
    size_t off  = grow*(size_t)NK + kt + tx*8;
    int4 m0 = *(const int4*)(mask + off);
    int4 m1 = *(const int4*)(mask + off + 4);
    float4 r0, r1;
    r0.x = m0.x ? NEG : acc[i][0]*INV;
    r0.y = m0.y ? NEG : acc[i][1]*INV;
    r0.z = m0.z ? NEG : acc[i][2]*INV;
    r0.w = m0.w ? NEG : acc[i][3]*INV;
    r1.x = m1.x ? NEG : acc[i][4]*INV;
    r1.y = m1.y ? NEG : acc[i][5]*INV;
    r1.z = m1.z ? NEG : acc[i][6]*INV;
    r1.w = m1.w ? NEG : acc[i][7]*INV;
    *(float4*)(S + off)     = r0;
    *(float4*)(S + off + 4) = r1;
  }
}

// ---------------- K2: per-row max and sum(exp(s-max)) -----------------------
__global__ __launch_bounds__(256) void k_stats(
    const float* __restrict__ S, float* __restrict__ ml) {
  size_t row = blockIdx.x;
  const float4* s = (const float4*)(S + row*(size_t)NK);
  int t = threadIdx.x;
  float4 u = s[t], w = s[t+256];
  float mx = fmaxf(fmaxf(fmaxf(u.x,u.y), fmaxf(u.z,u.w)),
                   fmaxf(fmaxf(w.x,w.y), fmaxf(w.z,w.w)));
  #pragma unroll
  for (int i = 1; i < 64; i <<= 1) mx = fmaxf(mx, __shfl_xor(mx, i));
  __shared__ float red[8];
  int wv = t >> 6, ln = t & 63;
  if (!ln) red[wv] = mx;
  __syncthreads();
  mx = fmaxf(fmaxf(red[0],red[1]), fmaxf(red[2],red[3]));
  float sm = __expf(u.x-mx)+__expf(u.y-mx)+__expf(u.z-mx)+__expf(u.w-mx)
           + __expf(w.x-mx)+__expf(w.y-mx)+__expf(w.z-mx)+__expf(w.w-mx);
  #pragma unroll
  for (int i = 1; i < 64; i <<= 1) sm += __shfl_xor(sm, i);
  if (!ln) red[4+wv] = sm;
  __syncthreads();
  if (!t) {
    ml[row]         = mx;
    ml[NROWS + row] = red[4]+red[5]+red[6]+red[7];
  }
}

// ---------------- K3: att = exp(S-m)/l (in place) ; ctx = att @ V -----------
// 128q x 128d tile per block; k-loop chunks of 32.
__global__ __launch_bounds__(256) void k_pv(
    float* __restrict__ satt, const float* __restrict__ v,
    const float* __restrict__ ml, float* __restrict__ ctx) {
  const int b  = blockIdx.y;
  const int qt = blockIdx.x << 7;
  __shared__ __align__(16) float Ps[32][132];  // [k][q]
  __shared__ __align__(16) float Vs[32][128];  // [k][d]
  __shared__ float Ms[128], Li[128];
  const int t  = threadIdx.x;
  const int ty = t >> 4, tx = t & 15;
  if (t < 128) {
    size_t r = (size_t)b*NQ + qt + t;
    Ms[t] = ml[r];
    Li[t] = 1.0f / ml[NROWS + r];
  }
  __syncthreads();
  float acc[8][8];
  #pragma unroll
  for (int i = 0; i < 8; i++)
    #pragma unroll
    for (int j = 0; j < 8; j++) acc[i][j] = 0.f;

  float* sb = satt + ((size_t)b*NQ + qt)*NK;
  const float* vb = v + (size_t)b*NK*DH;

  for (int k0 = 0; k0 < NK; k0 += 32) {
    #pragma unroll
    for (int e = 0; e < 16; e++) {
      int f = (e<<8) + t;
      int row = f >> 5, col = f & 31;     // q-row 0..127, k-col 0..31
      size_t off = (size_t)row*NK + k0 + col;
      float sv = sb[off];
      float p  = __expf(sv - Ms[row]) * Li[row];
      sb[off]  = p;                        // write normalized att
      Ps[col][row] = p;
    }
    #pragma unroll
    for (int e = 0; e < 16; e++) {
      int f = (e<<8) + t;
      int row = f >> 7, col = f & 127;    // k-row 0..31, d 0..127
      Vs[row][col] = vb[(size_t)(k0+row)*DH + col];
    }
    __syncthreads();
    #pragma unroll
    for (int kk = 0; kk < 32; kk++) {
      float av[8], bv[8];
      *(float4*)&av[0] = *(const float4*)&Ps[kk][ty*8];
      *(float4*)&av[4] = *(const float4*)&Ps[kk][ty*8+4];
      *(float4*)&bv[0] = *(const float4*)&Vs[kk][tx*8];
      *(float4*)&bv[4] = *(const float4*)&Vs[kk][tx*8+4];
      #pragma unroll
      for (int i = 0; i < 8; i++)
        #pragma unroll
        for (int j = 0; j < 8; j++)
          acc[i][j] = fmaf(av[i], bv[j], acc[i][j]);
    }
    __syncthreads();
  }

  float* cb = ctx + ((size_t)b*NQ + qt + ty*8)*(size_t)DH + tx*8;
  #pragma unroll
  for (int i = 0; i < 8; i++) {
    float4 r0 = {acc[i][0],acc[i][1],acc[i][2],acc[i][3]};
    float4 r1 = {acc[i][4],acc[i][5],acc[i][6],acc[i][7]};
    *(float4*)(cb + (size_t)i*DH)     = r0;
    *(float4*)(cb + (size_t)i*DH + 4) = r1;
  }
}

extern "C" void kernel_launch(void* const* d_in, const int* in_sizes, int n_in,
                              void* d_out, int out_size, void* d_ws, size_t ws_size,
                              hipStream_t stream) {
  const float* q = (const float*)d_in[0];
  const float* k = (const float*)d_in[1];
  const float* v = (const float*)d_in[2];
  const int* mask = (const int*)d_in[3];
  float* ctx = (float*)d_out;
  float* att = ctx + (size_t)B_*NQ*DH;   // outputs concatenated: context, att
  float* ml  = (float*)d_ws;             // [2*NROWS] floats: max, sumexp

  k_scores<<<dim3(NK/128, NQ/128, B_), 256, 0, stream>>>(q, k, mask, att);
  k_stats <<<NROWS, 256, 0, stream>>>(att, ml);
  k_pv    <<<dim3(NQ/128, B_), 256, 0, stream>>>(att, v, ml, ctx);
}

// Round 3
// 623.744 us; speedup vs baseline: 2.2505x; 2.2505x over previous
//
#include <hip/hip_runtime.h>

#define B_ 16
#define NQ 2048
#define NK 2048
#define DH 128
#define INV 0.08838834764831843f   // 1/sqrt(128)

typedef __attribute__((ext_vector_type(8))) short bf16x8;
typedef __attribute__((ext_vector_type(4))) float f32x4;

__device__ __forceinline__ unsigned short f2b(float f) {
  unsigned u = __float_as_uint(f);
  u += 0x7fff + ((u >> 16) & 1);          // RNE
  return (unsigned short)(u >> 16);
}

// ---------------- prep: fp32 -> bf16 cast (q, k) ----------------------------
__global__ __launch_bounds__(256) void k_cvt(
    const float* __restrict__ src, unsigned short* __restrict__ dst, int n4) {
  int i = blockIdx.x * 256 + threadIdx.x;
  if (i >= n4) return;
  float4 f = ((const float4*)src)[i];
  ushort4 u;
  u.x = f2b(f.x); u.y = f2b(f.y); u.z = f2b(f.z); u.w = f2b(f.w);
  ((ushort4*)dst)[i] = u;
}

// ---------------- prep: V [b][kv][d] -> Vt bf16 [b][d][kv] ------------------
__global__ __launch_bounds__(256) void k_trans(
    const float* __restrict__ v, unsigned short* __restrict__ vt) {
  __shared__ float tile[32][33];
  const int b = blockIdx.z, kv0 = blockIdx.x << 5, d0 = blockIdx.y << 5;
  const int tx = threadIdx.x & 31, ty = threadIdx.x >> 5;
  #pragma unroll
  for (int i = 0; i < 4; i++)
    tile[ty + 8*i][tx] = v[((size_t)b*NK + kv0 + ty + 8*i)*DH + d0 + tx];
  __syncthreads();
  #pragma unroll
  for (int i = 0; i < 4; i++)
    vt[((size_t)b*DH + d0 + ty + 8*i)*NK + kv0 + tx] = f2b(tile[tx][ty + 8*i]);
}

// ---------------- fused attention -------------------------------------------
// Block: 256 thr = 4 waves; owns 64 q-rows x full NK loop (kn tiles of 64).
// Sweep1: S=QK^T (MFMA) + row sumexp. Sweep2: recompute S, write att=exp(s)/l,
// P->LDS(bf16,A-layout), ctx += P @ V (MFMA via Vt).
__global__ __launch_bounds__(256) void k_attn(
    const unsigned short* __restrict__ qb, const unsigned short* __restrict__ kb,
    const unsigned short* __restrict__ vtb, const int* __restrict__ mask,
    float* __restrict__ att, float* __restrict__ ctx) {
  __shared__ unsigned short Qs[64][136];
  __shared__ unsigned short Ks[64][136];
  __shared__ unsigned short Vs[128][72];
  __shared__ unsigned short Ps[64][72];
  __shared__ float Lrow[64];

  const int t = threadIdx.x;
  const int wave = t >> 6, lane = t & 63, quad = lane >> 4, l15 = lane & 15;
  const int b = blockIdx.y, q0 = blockIdx.x << 6;
  const int qh = wave >> 1, nh = wave & 1;   // S: q-half/kn-half; PV: q-half/d-half

  const unsigned short* qg = qb  + ((size_t)b*NQ + q0)*DH;
  const unsigned short* kg = kb  + (size_t)b*NK*DH;
  const unsigned short* vg = vtb + (size_t)b*DH*NK;
  const int*   mg   = mask + ((size_t)b*NQ + q0)*NK;
  float*       attg = att  + ((size_t)b*NQ + q0)*NK;

  // stage Q once (64 x 128 bf16)
  {
    int r = t >> 2, c = (t & 3) << 5;
    const unsigned short* src = qg + (size_t)r*DH + c;
    #pragma unroll
    for (int i = 0; i < 4; i++)
      *(uint4*)&Qs[r][c + 8*i] = *(const uint4*)(src + 8*i);
  }
  if (t < 64) Lrow[t] = 0.f;

  float lsum[8] = {0,0,0,0,0,0,0,0};

  // ---------------- sweep 1: row sums of exp ----------------
  for (int k0 = 0; k0 < NK; k0 += 64) {
    __syncthreads();
    { int r = t >> 2, c = (t & 3) << 5;
      const unsigned short* src = kg + (size_t)(k0 + r)*DH + c;
      #pragma unroll
      for (int i = 0; i < 4; i++)
        *(uint4*)&Ks[r][c + 8*i] = *(const uint4*)(src + 8*i);
    }
    __syncthreads();
    f32x4 sa00 = 0, sa01 = 0, sa10 = 0, sa11 = 0;
    #pragma unroll
    for (int kd = 0; kd < 4; kd++) {
      bf16x8 a0 = *(const bf16x8*)&Qs[qh*32      + l15][kd*32 + quad*8];
      bf16x8 a1 = *(const bf16x8*)&Qs[qh*32 + 16 + l15][kd*32 + quad*8];
      bf16x8 b0 = *(const bf16x8*)&Ks[nh*32      + l15][kd*32 + quad*8];
      bf16x8 b1 = *(const bf16x8*)&Ks[nh*32 + 16 + l15][kd*32 + quad*8];
      sa00 = __builtin_amdgcn_mfma_f32_16x16x32_bf16(a0, b0, sa00, 0, 0, 0);
      sa01 = __builtin_amdgcn_mfma_f32_16x16x32_bf16(a0, b1, sa01, 0, 0, 0);
      sa10 = __builtin_amdgcn_mfma_f32_16x16x32_bf16(a1, b0, sa10, 0, 0, 0);
      sa11 = __builtin_amdgcn_mfma_f32_16x16x32_bf16(a1, b1, sa11, 0, 0, 0);
    }
    #pragma unroll
    for (int mt = 0; mt < 2; mt++)
      #pragma unroll
      for (int nt = 0; nt < 2; nt++) {
        const f32x4 s = mt ? (nt ? sa11 : sa10) : (nt ? sa01 : sa00);
        #pragma unroll
        for (int r = 0; r < 4; r++) {
          int row = qh*32 + mt*16 + quad*4 + r;
          int col = k0 + nh*32 + nt*16 + l15;
          int m = mg[(size_t)row*NK + col];
          float p = m ? 0.f : __expf(s[r]*INV);
          lsum[mt*4 + r] += p;
        }
      }
  }
  __syncthreads();
  #pragma unroll
  for (int j = 0; j < 8; j++)
    atomicAdd(&Lrow[qh*32 + (j>>2)*16 + quad*4 + (j&3)], lsum[j]);
  __syncthreads();
  float il[8];
  #pragma unroll
  for (int j = 0; j < 8; j++)
    il[j] = 1.0f / Lrow[qh*32 + (j>>2)*16 + quad*4 + (j&3)];

  // ---------------- sweep 2: att + ctx ----------------
  f32x4 ca[2][4];
  #pragma unroll
  for (int i = 0; i < 2; i++)
    #pragma unroll
    for (int j = 0; j < 4; j++) ca[i][j] = 0;

  for (int k0 = 0; k0 < NK; k0 += 64) {
    __syncthreads();
    { int r = t >> 2, c = (t & 3) << 5;
      const unsigned short* src = kg + (size_t)(k0 + r)*DH + c;
      #pragma unroll
      for (int i = 0; i < 4; i++)
        *(uint4*)&Ks[r][c + 8*i] = *(const uint4*)(src + 8*i);
      int d = t >> 1, c2 = (t & 1) << 5;
      const unsigned short* vsrc = vg + (size_t)d*NK + k0 + c2;
      #pragma unroll
      for (int i = 0; i < 4; i++)
        *(uint4*)&Vs[d][c2 + 8*i] = *(const uint4*)(vsrc + 8*i);
    }
    __syncthreads();
    f32x4 sa00 = 0, sa01 = 0, sa10 = 0, sa11 = 0;
    #pragma unroll
    for (int kd = 0; kd < 4; kd++) {
      bf16x8 a0 = *(const bf16x8*)&Qs[qh*32      + l15][kd*32 + quad*8];
      bf16x8 a1 = *(const bf16x8*)&Qs[qh*32 + 16 + l15][kd*32 + quad*8];
      bf16x8 b0 = *(const bf16x8*)&Ks[nh*32      + l15][kd*32 + quad*8];
      bf16x8 b1 = *(const bf16x8*)&Ks[nh*32 + 16 + l15][kd*32 + quad*8];
      sa00 = __builtin_amdgcn_mfma_f32_16x16x32_bf16(a0, b0, sa00, 0, 0, 0);
      sa01 = __builtin_amdgcn_mfma_f32_16x16x32_bf16(a0, b1, sa01, 0, 0, 0);
      sa10 = __builtin_amdgcn_mfma_f32_16x16x32_bf16(a1, b0, sa10, 0, 0, 0);
      sa11 = __builtin_amdgcn_mfma_f32_16x16x32_bf16(a1, b1, sa11, 0, 0, 0);
    }
    #pragma unroll
    for (int mt = 0; mt < 2; mt++)
      #pragma unroll
      for (int nt = 0; nt < 2; nt++) {
        const f32x4 s = mt ? (nt ? sa11 : sa10) : (nt ? sa01 : sa00);
        #pragma unroll
        for (int r = 0; r < 4; r++) {
          int row = qh*32 + mt*16 + quad*4 + r;
          int coll = nh*32 + nt*16 + l15;
          int m = mg[(size_t)row*NK + k0 + coll];
          float p = m ? 0.f : __expf(s[r]*INV) * il[mt*4 + r];
          attg[(size_t)row*NK + k0 + coll] = p;
          Ps[row][coll] = f2b(p);
        }
      }
    __syncthreads();
    #pragma unroll
    for (int kv = 0; kv < 2; kv++) {
      bf16x8 pa0 = *(const bf16x8*)&Ps[qh*32      + l15][kv*32 + quad*8];
      bf16x8 pa1 = *(const bf16x8*)&Ps[qh*32 + 16 + l15][kv*32 + quad*8];
      #pragma unroll
      for (int dt = 0; dt < 4; dt++) {
        bf16x8 vb = *(const bf16x8*)&Vs[nh*64 + dt*16 + l15][kv*32 + quad*8];
        ca[0][dt] = __builtin_amdgcn_mfma_f32_16x16x32_bf16(pa0, vb, ca[0][dt], 0, 0, 0);
        ca[1][dt] = __builtin_amdgcn_mfma_f32_16x16x32_bf16(pa1, vb, ca[1][dt], 0, 0, 0);
      }
    }
  }

  float* cg = ctx + ((size_t)b*NQ + q0)*DH;
  #pragma unroll
  for (int mt = 0; mt < 2; mt++)
    #pragma unroll
    for (int dt = 0; dt < 4; dt++)
      #pragma unroll
      for (int r = 0; r < 4; r++) {
        int row = qh*32 + mt*16 + quad*4 + r;
        int col = nh*64 + dt*16 + l15;
        cg[(size_t)row*DH + col] = ca[mt][dt][r];
      }
}

extern "C" void kernel_launch(void* const* d_in, const int* in_sizes, int n_in,
                              void* d_out, int out_size, void* d_ws, size_t ws_size,
                              hipStream_t stream) {
  const float* q = (const float*)d_in[0];
  const float* k = (const float*)d_in[1];
  const float* v = (const float*)d_in[2];
  const int* mask = (const int*)d_in[3];
  float* ctx = (float*)d_out;
  float* att = ctx + (size_t)B_*NQ*DH;

  const size_t NE = (size_t)B_*NQ*DH;      // 4.19M elements per tensor
  unsigned short* qws = (unsigned short*)d_ws;
  unsigned short* kws = qws + NE;
  unsigned short* vws = kws + NE;

  k_cvt  <<<(int)(NE/1024), 256, 0, stream>>>(q, qws, (int)(NE/4));
  k_cvt  <<<(int)(NE/1024), 256, 0, stream>>>(k, kws, (int)(NE/4));
  k_trans<<<dim3(NK/32, DH/32, B_), 256, 0, stream>>>(v, vws);
  k_attn <<<dim3(NQ/64, B_), 256, 0, stream>>>(qws, kws, vws, mask, att, ctx);
}

// Round 4
// 602.770 us; speedup vs baseline: 2.3288x; 1.0348x over previous
//
#include <hip/hip_runtime.h>

#define B_ 16
#define NQ 2048
#define NK 2048
#define DH 128
#define INV 0.08838834764831843f   // 1/sqrt(128)

typedef __attribute__((ext_vector_type(8))) short bf16x8;
typedef __attribute__((ext_vector_type(4))) float f32x4;

__device__ __forceinline__ unsigned short f2b(float f) {
  unsigned u = __float_as_uint(f);
  u += 0x7fff + ((u >> 16) & 1);          // RNE
  return (unsigned short)(u >> 16);
}

// ---------------- prep: fp32 -> bf16 cast (q, k) ----------------------------
__global__ __launch_bounds__(256) void k_cvt(
    const float* __restrict__ src, unsigned short* __restrict__ dst, int n4) {
  int i = blockIdx.x * 256 + threadIdx.x;
  if (i >= n4) return;
  float4 f = ((const float4*)src)[i];
  ushort4 u;
  u.x = f2b(f.x); u.y = f2b(f.y); u.z = f2b(f.z); u.w = f2b(f.w);
  ((ushort4*)dst)[i] = u;
}

// ---------------- prep: V [b][kv][d] -> Vt bf16 [b][d][kv] ------------------
__global__ __launch_bounds__(256) void k_trans(
    const float* __restrict__ v, unsigned short* __restrict__ vt) {
  __shared__ float tile[32][33];
  const int b = blockIdx.z, kv0 = blockIdx.x << 5, d0 = blockIdx.y << 5;
  const int tx = threadIdx.x & 31, ty = threadIdx.x >> 5;
  #pragma unroll
  for (int i = 0; i < 4; i++)
    tile[ty + 8*i][tx] = v[((size_t)b*NK + kv0 + ty + 8*i)*DH + d0 + tx];
  __syncthreads();
  #pragma unroll
  for (int i = 0; i < 4; i++)
    vt[((size_t)b*DH + d0 + ty + 8*i)*NK + kv0 + tx] = f2b(tile[tx][ty + 8*i]);
}

// ---------------- fused attention -------------------------------------------
// Block: 256 thr = 4 waves; 64 q-rows x full NK loop (tiles of 64).
// Sweep1: S=QK^T (MFMA), row sumexp; mask int32 read ONCE, bit-packed into
//         LDS Mb via ballot (block-private strip: 64 rows x 2048 bits).
// Sweep2: recompute S, mask from LDS bits (broadcast), write att=exp(s)/l,
//         P->LDS bf16 (A-layout), ctx += P @ V via Vt.
__global__ __launch_bounds__(256) void k_attn(
    const unsigned short* __restrict__ qb, const unsigned short* __restrict__ kb,
    const unsigned short* __restrict__ vtb, const int* __restrict__ mask,
    float* __restrict__ att, float* __restrict__ ctx) {
  __shared__ unsigned short Qs[64][136];
  __shared__ unsigned short Ks[64][136];
  __shared__ unsigned short Vs[128][72];
  __shared__ unsigned short Ps[64][72];
  __shared__ unsigned int   Mb[64][65];   // bit-packed mask [row][word], pad 65
  __shared__ float Lrow[64];

  const int t = threadIdx.x;
  const int wave = t >> 6, lane = t & 63, quad = lane >> 4, l15 = lane & 15;
  const int b = blockIdx.y, q0 = blockIdx.x << 6;
  const int qh = wave >> 1, nh = wave & 1;

  const unsigned short* qg = qb  + ((size_t)b*NQ + q0)*DH;
  const unsigned short* kg = kb  + (size_t)b*NK*DH;
  const unsigned short* vg = vtb + (size_t)b*DH*NK;
  const int*   mg   = mask + ((size_t)b*NQ + q0)*NK;
  float*       attg = att  + ((size_t)b*NQ + q0)*NK;

  // stage Q once (64 x 128 bf16)
  {
    int r = t >> 2, c = (t & 3) << 5;
    const unsigned short* src = qg + (size_t)r*DH + c;
    #pragma unroll
    for (int i = 0; i < 4; i++)
      *(uint4*)&Qs[r][c + 8*i] = *(const uint4*)(src + 8*i);
  }
  if (t < 64) Lrow[t] = 0.f;

  float lsum[8] = {0,0,0,0,0,0,0,0};

  // ---------------- sweep 1: row sums of exp + mask bit-pack ----------------
  for (int k0 = 0; k0 < NK; k0 += 64) {
    // prefetch this tile's mask ints (latency overlaps staging+barrier+MFMA)
    int mreg[2][2][4];
    #pragma unroll
    for (int mt = 0; mt < 2; mt++)
      #pragma unroll
      for (int nt = 0; nt < 2; nt++)
        #pragma unroll
        for (int r = 0; r < 4; r++) {
          int row = qh*32 + mt*16 + quad*4 + r;
          int col = k0 + nh*32 + nt*16 + l15;
          mreg[mt][nt][r] = mg[(size_t)row*NK + col];
        }
    __syncthreads();
    { int r = t >> 2, c = (t & 3) << 5;
      const unsigned short* src = kg + (size_t)(k0 + r)*DH + c;
      #pragma unroll
      for (int i = 0; i < 4; i++)
        *(uint4*)&Ks[r][c + 8*i] = *(const uint4*)(src + 8*i);
    }
    __syncthreads();
    f32x4 sa00 = 0, sa01 = 0, sa10 = 0, sa11 = 0;
    #pragma unroll
    for (int kd = 0; kd < 4; kd++) {
      bf16x8 a0 = *(const bf16x8*)&Qs[qh*32      + l15][kd*32 + quad*8];
      bf16x8 a1 = *(const bf16x8*)&Qs[qh*32 + 16 + l15][kd*32 + quad*8];
      bf16x8 b0 = *(const bf16x8*)&Ks[nh*32      + l15][kd*32 + quad*8];
      bf16x8 b1 = *(const bf16x8*)&Ks[nh*32 + 16 + l15][kd*32 + quad*8];
      sa00 = __builtin_amdgcn_mfma_f32_16x16x32_bf16(a0, b0, sa00, 0, 0, 0);
      sa01 = __builtin_amdgcn_mfma_f32_16x16x32_bf16(a0, b1, sa01, 0, 0, 0);
      sa10 = __builtin_amdgcn_mfma_f32_16x16x32_bf16(a1, b0, sa10, 0, 0, 0);
      sa11 = __builtin_amdgcn_mfma_f32_16x16x32_bf16(a1, b1, sa11, 0, 0, 0);
    }
    #pragma unroll
    for (int mt = 0; mt < 2; mt++)
      #pragma unroll
      for (int nt = 0; nt < 2; nt++) {
        const f32x4 s = mt ? (nt ? sa11 : sa10) : (nt ? sa01 : sa00);
        #pragma unroll
        for (int r = 0; r < 4; r++) {
          bool mm = mreg[mt][nt][r] != 0;
          unsigned long long bal = __ballot(mm);
          if (l15 == 0) {   // lanes 0,16,32,48 write their quad's 16 cols
            int row = qh*32 + mt*16 + quad*4 + r;
            ((unsigned short*)&Mb[0][0])[row*130 + (k0>>4) + nh*2 + nt] =
                (unsigned short)(bal >> (quad*16));
          }
          float p = mm ? 0.f : __expf(s[r]*INV);
          lsum[mt*4 + r] += p;
        }
      }
  }
  __syncthreads();
  #pragma unroll
  for (int j = 0; j < 8; j++)
    atomicAdd(&Lrow[qh*32 + (j>>2)*16 + quad*4 + (j&3)], lsum[j]);
  __syncthreads();
  float il[8];
  #pragma unroll
  for (int j = 0; j < 8; j++)
    il[j] = 1.0f / Lrow[qh*32 + (j>>2)*16 + quad*4 + (j&3)];

  // ---------------- sweep 2: att + ctx (mask from LDS bits) ----------------
  f32x4 ca[2][4];
  #pragma unroll
  for (int i = 0; i < 2; i++)
    #pragma unroll
    for (int j = 0; j < 4; j++) ca[i][j] = 0;

  for (int k0 = 0; k0 < NK; k0 += 64) {
    __syncthreads();
    { int r = t >> 2, c = (t & 3) << 5;
      const unsigned short* src = kg + (size_t)(k0 + r)*DH + c;
      #pragma unroll
      for (int i = 0; i < 4; i++)
        *(uint4*)&Ks[r][c + 8*i] = *(const uint4*)(src + 8*i);
      int d = t >> 1, c2 = (t & 1) << 5;
      const unsigned short* vsrc = vg + (size_t)d*NK + k0 + c2;
      #pragma unroll
      for (int i = 0; i < 4; i++)
        *(uint4*)&Vs[d][c2 + 8*i] = *(const uint4*)(vsrc + 8*i);
    }
    __syncthreads();
    f32x4 sa00 = 0, sa01 = 0, sa10 = 0, sa11 = 0;
    #pragma unroll
    for (int kd = 0; kd < 4; kd++) {
      bf16x8 a0 = *(const bf16x8*)&Qs[qh*32      + l15][kd*32 + quad*8];
      bf16x8 a1 = *(const bf16x8*)&Qs[qh*32 + 16 + l15][kd*32 + quad*8];
      bf16x8 b0 = *(const bf16x8*)&Ks[nh*32      + l15][kd*32 + quad*8];
      bf16x8 b1 = *(const bf16x8*)&Ks[nh*32 + 16 + l15][kd*32 + quad*8];
      sa00 = __builtin_amdgcn_mfma_f32_16x16x32_bf16(a0, b0, sa00, 0, 0, 0);
      sa01 = __builtin_amdgcn_mfma_f32_16x16x32_bf16(a0, b1, sa01, 0, 0, 0);
      sa10 = __builtin_amdgcn_mfma_f32_16x16x32_bf16(a1, b0, sa10, 0, 0, 0);
      sa11 = __builtin_amdgcn_mfma_f32_16x16x32_bf16(a1, b1, sa11, 0, 0, 0);
    }
    #pragma unroll
    for (int mt = 0; mt < 2; mt++)
      #pragma unroll
      for (int nt = 0; nt < 2; nt++) {
        const f32x4 s = mt ? (nt ? sa11 : sa10) : (nt ? sa01 : sa00);
        #pragma unroll
        for (int r = 0; r < 4; r++) {
          int row  = qh*32 + mt*16 + quad*4 + r;
          int coll = nh*32 + nt*16 + l15;
          unsigned w = Mb[row][(k0>>5) + nh];
          int bit = (w >> (nt*16 + l15)) & 1;
          float p = bit ? 0.f : __expf(s[r]*INV) * il[mt*4 + r];
          attg[(size_t)row*NK + k0 + coll] = p;
          Ps[row][coll] = f2b(p);
        }
      }
    __syncthreads();
    #pragma unroll
    for (int kv = 0; kv < 2; kv++) {
      bf16x8 pa0 = *(const bf16x8*)&Ps[qh*32      + l15][kv*32 + quad*8];
      bf16x8 pa1 = *(const bf16x8*)&Ps[qh*32 + 16 + l15][kv*32 + quad*8];
      #pragma unroll
      for (int dt = 0; dt < 4; dt++) {
        bf16x8 vb = *(const bf16x8*)&Vs[nh*64 + dt*16 + l15][kv*32 + quad*8];
        ca[0][dt] = __builtin_amdgcn_mfma_f32_16x16x32_bf16(pa0, vb, ca[0][dt], 0, 0, 0);
        ca[1][dt] = __builtin_amdgcn_mfma_f32_16x16x32_bf16(pa1, vb, ca[1][dt], 0, 0, 0);
      }
    }
  }

  float* cg = ctx + ((size_t)b*NQ + q0)*DH;
  #pragma unroll
  for (int mt = 0; mt < 2; mt++)
    #pragma unroll
    for (int dt = 0; dt < 4; dt++)
      #pragma unroll
      for (int r = 0; r < 4; r++) {
        int row = qh*32 + mt*16 + quad*4 + r;
        int col = nh*64 + dt*16 + l15;
        cg[(size_t)row*DH + col] = ca[mt][dt][r];
      }
}

extern "C" void kernel_launch(void* const* d_in, const int* in_sizes, int n_in,
                              void* d_out, int out_size, void* d_ws, size_t ws_size,
                              hipStream_t stream) {
  const float* q = (const float*)d_in[0];
  const float* k = (const float*)d_in[1];
  const float* v = (const float*)d_in[2];
  const int* mask = (const int*)d_in[3];
  float* ctx = (float*)d_out;
  float* att = ctx + (size_t)B_*NQ*DH;

  const size_t NE = (size_t)B_*NQ*DH;
  unsigned short* qws = (unsigned short*)d_ws;
  unsigned short* kws = qws + NE;
  unsigned short* vws = kws + NE;

  k_cvt  <<<(int)(NE/1024), 256, 0, stream>>>(q, qws, (int)(NE/4));
  k_cvt  <<<(int)(NE/1024), 256, 0, stream>>>(k, kws, (int)(NE/4));
  k_trans<<<dim3(NK/32, DH/32, B_), 256, 0, stream>>>(v, vws);
  k_attn <<<dim3(NQ/64, B_), 256, 0, stream>>>(qws, kws, vws, mask, att, ctx);
}